// Round 2
// baseline (3544.327 us; speedup 1.0000x reference)
//
#include <hip/hip_runtime.h>
#include <hip/hip_bf16.h>

#define B_SZ 16
#define CIN 256
#define EDIM 256
#define NE 8192
#define HW 32
#define NPIX (B_SZ*HW*HW)          // 16384
#define OUT_ELEMS (B_SZ*CIN*HW*HW) // 4194304

// ---------------- block reduction helpers ----------------
__device__ __forceinline__ float block_sum(float v, float* sbuf) {
    #pragma unroll
    for (int off = 32; off > 0; off >>= 1) v += __shfl_down(v, off, 64);
    int wid = threadIdx.x >> 6;
    int lane = threadIdx.x & 63;
    if (lane == 0) sbuf[wid] = v;
    __syncthreads();
    if (threadIdx.x == 0) sbuf[0] = sbuf[0] + sbuf[1] + sbuf[2] + sbuf[3];
    __syncthreads();
    float r = sbuf[0];
    __syncthreads();
    return r;
}

__device__ __forceinline__ double block_sum_d(double v, double* sbuf) {
    #pragma unroll
    for (int off = 32; off > 0; off >>= 1) v += __shfl_down(v, off, 64);
    int wid = threadIdx.x >> 6;
    int lane = threadIdx.x & 63;
    if (lane == 0) sbuf[wid] = v;
    __syncthreads();
    if (threadIdx.x == 0) sbuf[0] = (sbuf[0] + sbuf[1]) + (sbuf[2] + sbuf[3]);
    __syncthreads();
    double r = sbuf[0];
    __syncthreads();
    return r;
}

// ---------------- weight repack: dst[k*256 + o] = src[o*2304 + k] ----------------
__global__ void repack_w_kernel(const float* __restrict__ src, float* __restrict__ dst) {
    int k = blockIdx.x;      // 0..2303
    int o = threadIdx.x;     // 0..255
    dst[(size_t)k * 256 + o] = src[(size_t)o * 2304 + k];
}

// ---------------- codebook repack: cbT4[((k>>2)*8192 + n)*4 + (k&3)] = cb[n*256+k] ----------------
__global__ void cb_repack4_kernel(const float* __restrict__ cb, float* __restrict__ cbT4) {
    int i = blockIdx.x * 256 + threadIdx.x;   // 0 .. 2M-1
    int n = i >> 8, k = i & 255;
    float v = cb[i];
    cbT4[((size_t)(k >> 2) * 8192 + n) * 4 + (k & 3)] = v;
}

// ---------------- emb conv: z[B,C,H,W] -> ze[(b,h,w), e], f64-folded accumulation ----------------
__global__ __launch_bounds__(256) void conv_emb_kernel(const float* __restrict__ z,
                                                       const float* __restrict__ w1t,
                                                       const float* __restrict__ bias,
                                                       float* __restrict__ ze) {
    __shared__ float s[3 * 64 * 36];
    int bh = blockIdx.x;            // 0..511
    int b = bh >> 5, h = bh & 31;
    int e = threadIdx.x;
    double accd[32];
    #pragma unroll
    for (int w = 0; w < 32; ++w) accd[w] = 0.0;
    for (int i = threadIdx.x; i < 3 * 64 * 36; i += 256) s[i] = 0.f;
    __syncthreads();

    for (int cc = 0; cc < 256; cc += 64) {
        for (int i = threadIdx.x; i < 3 * 64 * 32; i += 256) {
            int r = i >> 11;
            int c = (i >> 5) & 63;
            int w = i & 31;
            int hh = h + r - 1;
            float v = 0.f;
            if (hh >= 0 && hh < 32) v = z[(size_t)b * 262144 + (size_t)(cc + c) * 1024 + hh * 32 + w];
            s[(r * 64 + c) * 36 + (w + 1)] = v;
        }
        __syncthreads();
        for (int c = 0; c < 64; ++c) {
            const float* wrow = w1t + (size_t)(cc + c) * 9 * 256 + e;
            float tmp[32];
            #pragma unroll
            for (int w = 0; w < 32; ++w) tmp[w] = 0.f;
            #pragma unroll
            for (int r = 0; r < 3; ++r) {
                float v[36];
                const float* lrow = s + (r * 64 + c) * 36;
                #pragma unroll
                for (int q = 0; q < 9; ++q) {
                    float4 t4 = *(const float4*)(lrow + q * 4);
                    v[q * 4 + 0] = t4.x; v[q * 4 + 1] = t4.y; v[q * 4 + 2] = t4.z; v[q * 4 + 3] = t4.w;
                }
                #pragma unroll
                for (int kw = 0; kw < 3; ++kw) {
                    float wv = wrow[(r * 3 + kw) * 256];
                    #pragma unroll
                    for (int w = 0; w < 32; ++w) tmp[w] = fmaf(v[w + kw], wv, tmp[w]);
                }
            }
            #pragma unroll
            for (int w = 0; w < 32; ++w) accd[w] += (double)tmp[w];
        }
        __syncthreads();
    }
    float bv = bias[e];
    int p0 = (b * 32 + h) * 32;
    #pragma unroll
    for (int w = 0; w < 32; ++w) ze[(size_t)(p0 + w) * 256 + e] = (float)accd[w] + bv;
}

// ---------------- layernorm over E=256, replicating numpy's fp32 rounding points ----------------
// Also emits snorm[p] = fl32(sum(zf^2)) per row.
__global__ void ln_kernel(const float* __restrict__ ze, const float* __restrict__ g,
                          const float* __restrict__ bta, float* __restrict__ zf,
                          float* __restrict__ snorm) {
    __shared__ double sbuf[4];
    int p = blockIdx.x; int t = threadIdx.x;
    float x = ze[(size_t)p * 256 + t];
    double sum = block_sum_d((double)x, sbuf);
    float mu = ((float)sum) / 256.0f;           // fl32(sum) / 256 (exact div)
    float dev = x - mu;                          // fp32 like np
    float sq = dev * dev;                        // fp32 square like np
    double vs = block_sum_d((double)sq, sbuf);
    float var = ((float)vs) / 256.0f;
    float r = 1.0f / sqrtf(var + 1e-5f);         // correctly-rounded sqrt + div
    float y = ((dev * r) * g[t]) + bta[t];       // np op order; g=1,b=0 are exact no-ops
    zf[(size_t)p * 256 + t] = y;
    float ysq = y * y;                           // fp32 square like np's zf**2
    double ss = block_sum_d((double)ysq, sbuf);
    if (t == 0) snorm[p] = (float)ss;
}

// ---------------- distance + argmin, replicating np's fp32 quantized d ----------------
// d_n = fl32(s_z - 2*fl32(dot_n)) ; ||e||^2 provably absorbed (< half-ulp of s_z).
// First-index tie-break like np.argmin.
__global__ __launch_bounds__(256) void dist_kernel(const float* __restrict__ zf,
                                                   const float* __restrict__ cbT4,
                                                   const float* __restrict__ snorm,
                                                   int* __restrict__ idx_i,
                                                   float* __restrict__ idx_f) {
    __shared__ float sT[256 * 16];
    __shared__ float ssz[16];
    __shared__ float cval[4][16];
    __shared__ int   cidx[4][16];
    int p0 = blockIdx.x * 16;
    int tid = threadIdx.x;
    for (int i = tid; i < 4096; i += 256) {
        int pp = i >> 8, k = i & 255;
        sT[k * 16 + pp] = zf[(size_t)(p0 + pp) * 256 + k];
    }
    if (tid < 16) ssz[tid] = snorm[p0 + tid];
    __syncthreads();

    float best[16]; int bidx[16];
    #pragma unroll
    for (int pp = 0; pp < 16; ++pp) { best[pp] = 3.4e38f; bidx[pp] = 0; }

    const float4* cbv = (const float4*)cbT4;
    for (int chunk = 0; chunk < 32; ++chunk) {
        int n = (chunk << 8) + tid;
        float a[4][16];
        #pragma unroll
        for (int j = 0; j < 4; ++j)
            #pragma unroll
            for (int pp = 0; pp < 16; ++pp) a[j][pp] = 0.f;

        #pragma unroll 2
        for (int k0 = 0; k0 < 256; k0 += 4) {
            float4 c4 = cbv[(size_t)(k0 >> 2) * 8192 + n];
            #pragma unroll
            for (int j = 0; j < 4; ++j) {
                float cj = (j == 0) ? c4.x : (j == 1) ? c4.y : (j == 2) ? c4.z : c4.w;
                const float* srow = sT + (k0 + j) * 16;
                #pragma unroll
                for (int q = 0; q < 8; ++q) {
                    float2 sv = *(const float2*)(srow + 2 * q);
                    a[j][2 * q]     = fmaf(sv.x, cj, a[j][2 * q]);
                    a[j][2 * q + 1] = fmaf(sv.y, cj, a[j][2 * q + 1]);
                }
            }
        }
        #pragma unroll
        for (int pp = 0; pp < 16; ++pp) {
            float dot32 = (float)(((double)a[0][pp] + (double)a[1][pp]) +
                                  ((double)a[2][pp] + (double)a[3][pp]));
            float d = fmaf(-2.0f, dot32, ssz[pp]);   // single rounding == np's fl(s_z - 2*dot32)
            if (d < best[pp]) { best[pp] = d; bidx[pp] = n; }
        }
    }

    int lane = tid & 63, wid = tid >> 6;
    #pragma unroll
    for (int pp = 0; pp < 16; ++pp) {
        float v = best[pp]; int ix = bidx[pp];
        #pragma unroll
        for (int off = 32; off > 0; off >>= 1) {
            float ov = __shfl_down(v, off, 64);
            int   oi = __shfl_down(ix, off, 64);
            if (ov < v || (ov == v && oi < ix)) { v = ov; ix = oi; }
        }
        if (lane == 0) { cval[wid][pp] = v; cidx[wid][pp] = ix; }
    }
    __syncthreads();
    if (tid < 16) {
        int pp = tid;
        float v = cval[0][pp]; int ix = cidx[0][pp];
        #pragma unroll
        for (int w2 = 1; w2 < 4; ++w2) {
            float ov = cval[w2][pp]; int oi = cidx[w2][pp];
            if (ov < v || (ov == v && oi < ix)) { v = ov; ix = oi; }
        }
        idx_i[p0 + pp] = ix;
        idx_f[p0 + pp] = (float)ix;
    }
}

// ---------------- loss ----------------
__global__ void loss_partial_kernel(const float* __restrict__ ze, const float* __restrict__ cb,
                                    const int* __restrict__ idx, float* __restrict__ partials) {
    __shared__ float sbuf[4];
    float sum = 0.f;
    const int total = NPIX * 256;
    for (int i = blockIdx.x * blockDim.x + threadIdx.x; i < total; i += gridDim.x * blockDim.x) {
        int p = i >> 8;
        int e = i & 255;
        float d = cb[(size_t)idx[p] * 256 + e] - ze[i];
        sum = fmaf(d, d, sum);
    }
    sum = block_sum(sum, sbuf);
    if (threadIdx.x == 0) partials[blockIdx.x] = sum;
}

__global__ void loss_final_kernel(const float* __restrict__ partials, float* __restrict__ loss_out) {
    __shared__ float sbuf[4];
    float v = partials[threadIdx.x];
    v = block_sum(v, sbuf);
    if (threadIdx.x == 0) *loss_out = v * (1.25f / (float)(NPIX * 256));
}

// ---------------- unemb conv: gather codebook[idx] as [b,h,w,e] -> out[B,C,H,W] ----------------
__global__ __launch_bounds__(256) void conv_unemb_kernel(const float* __restrict__ cb,
                                                         const int* __restrict__ idx,
                                                         const float* __restrict__ w2t,
                                                         const float* __restrict__ bias,
                                                         float* __restrict__ out) {
    __shared__ float s[3 * 64 * 36];
    int bh = blockIdx.x;
    int b = bh >> 5, h = bh & 31;
    int cth = threadIdx.x;           // output channel
    float acc[32];
    #pragma unroll
    for (int w = 0; w < 32; ++w) acc[w] = 0.f;
    for (int i = threadIdx.x; i < 3 * 64 * 36; i += 256) s[i] = 0.f;
    __syncthreads();

    for (int cc = 0; cc < 256; cc += 64) {   // e chunk
        for (int i = threadIdx.x; i < 3 * 32 * 64; i += 256) {
            int r = i >> 11;
            int w = (i >> 6) & 31;
            int ee = i & 63;
            int hh = h + r - 1;
            float v = 0.f;
            if (hh >= 0 && hh < 32) {
                int p = (b * 32 + hh) * 32 + w;
                v = cb[(size_t)idx[p] * 256 + cc + ee];
            }
            s[(r * 64 + ee) * 36 + (w + 1)] = v;
        }
        __syncthreads();
        for (int ee = 0; ee < 64; ++ee) {
            const float* wrow = w2t + (size_t)(cc + ee) * 9 * 256 + cth;
            #pragma unroll
            for (int r = 0; r < 3; ++r) {
                float v[36];
                const float* lrow = s + (r * 64 + ee) * 36;
                #pragma unroll
                for (int q = 0; q < 9; ++q) {
                    float4 t4 = *(const float4*)(lrow + q * 4);
                    v[q * 4 + 0] = t4.x; v[q * 4 + 1] = t4.y; v[q * 4 + 2] = t4.z; v[q * 4 + 3] = t4.w;
                }
                #pragma unroll
                for (int kw = 0; kw < 3; ++kw) {
                    float wv = wrow[(r * 3 + kw) * 256];
                    #pragma unroll
                    for (int w = 0; w < 32; ++w) acc[w] = fmaf(v[w + kw], wv, acc[w]);
                }
            }
        }
        __syncthreads();
    }
    float bv = bias[cth];
    float* orow = out + ((size_t)(b * 256 + cth) * 32 + h) * 32;
    #pragma unroll
    for (int w = 0; w < 32; ++w) orow[w] = acc[w] + bv;
}

extern "C" void kernel_launch(void* const* d_in, const int* in_sizes, int n_in,
                              void* d_out, int out_size, void* d_ws, size_t ws_size,
                              hipStream_t stream) {
    const float* z       = (const float*)d_in[0];
    const float* emb_w   = (const float*)d_in[1];
    const float* emb_b   = (const float*)d_in[2];
    const float* ln_g    = (const float*)d_in[3];
    const float* ln_b    = (const float*)d_in[4];
    const float* cb      = (const float*)d_in[5];
    const float* unemb_w = (const float*)d_in[6];
    const float* unemb_b = (const float*)d_in[7];

    float* out    = (float*)d_out;                    // [16,256,32,32]
    float* lossp  = out + OUT_ELEMS;                  // scalar
    float* idxf   = out + OUT_ELEMS + 1;              // [16384] as float

    // workspace layout (floats)
    float* ws    = (float*)d_ws;
    float* ze_t  = ws;                                // 4,194,304
    float* zf    = ze_t + (size_t)NPIX * 256;         // 4,194,304
    float* cbT4  = zf + (size_t)NPIX * 256;           // 2,097,152
    float* snorm = cbT4 + (size_t)NE * 256;           // 16,384
    float* w1t   = snorm + NPIX;                      // 589,824
    float* w2t   = w1t + 2304 * 256;                  // 589,824
    int*   idxi  = (int*)(w2t + 2304 * 256);          // 16,384
    float* partials = (float*)(idxi + NPIX);          // 256

    hipLaunchKernelGGL(repack_w_kernel, dim3(2304), dim3(256), 0, stream, emb_w, w1t);
    hipLaunchKernelGGL(repack_w_kernel, dim3(2304), dim3(256), 0, stream, unemb_w, w2t);
    hipLaunchKernelGGL(cb_repack4_kernel, dim3(8192), dim3(256), 0, stream, cb, cbT4);
    hipLaunchKernelGGL(conv_emb_kernel, dim3(512), dim3(256), 0, stream, z, w1t, emb_b, ze_t);
    hipLaunchKernelGGL(ln_kernel, dim3(NPIX), dim3(256), 0, stream, ze_t, ln_g, ln_b, zf, snorm);
    hipLaunchKernelGGL(dist_kernel, dim3(1024), dim3(256), 0, stream, zf, cbT4, snorm, idxi, idxf);
    hipLaunchKernelGGL(loss_partial_kernel, dim3(256), dim3(256), 0, stream, ze_t, cb, idxi, partials);
    hipLaunchKernelGGL(loss_final_kernel, dim3(1), dim3(256), 0, stream, partials, lossp);
    hipLaunchKernelGGL(conv_unemb_kernel, dim3(512), dim3(256), 0, stream, cb, idxi, w2t, unemb_b, out);
}

// Round 3
// 1525.166 us; speedup vs baseline: 2.3239x; 2.3239x over previous
//
#include <hip/hip_runtime.h>
#include <hip/hip_bf16.h>

#define B_SZ 16
#define CIN 256
#define EDIM 256
#define NE 8192
#define HW 32
#define NPIX (B_SZ*HW*HW)          // 16384
#define OUT_ELEMS (B_SZ*CIN*HW*HW) // 4194304
#define SCREEN_T 3.2e-4f
#define CAND_SLOTS 32

typedef __attribute__((ext_vector_type(8))) short short8;
typedef __attribute__((ext_vector_type(4))) short short4v;
typedef __attribute__((ext_vector_type(4))) float f32x4;

// ---------------- helpers ----------------
__device__ __forceinline__ float block_sum(float v, float* sbuf) {
    #pragma unroll
    for (int off = 32; off > 0; off >>= 1) v += __shfl_down(v, off, 64);
    int wid = threadIdx.x >> 6;
    int lane = threadIdx.x & 63;
    if (lane == 0) sbuf[wid] = v;
    __syncthreads();
    if (threadIdx.x == 0) sbuf[0] = sbuf[0] + sbuf[1] + sbuf[2] + sbuf[3];
    __syncthreads();
    float r = sbuf[0];
    __syncthreads();
    return r;
}

__device__ __forceinline__ double block_sum_d(double v, double* sbuf) {
    #pragma unroll
    for (int off = 32; off > 0; off >>= 1) v += __shfl_down(v, off, 64);
    int wid = threadIdx.x >> 6;
    int lane = threadIdx.x & 63;
    if (lane == 0) sbuf[wid] = v;
    __syncthreads();
    if (threadIdx.x == 0) sbuf[0] = (sbuf[0] + sbuf[1]) + (sbuf[2] + sbuf[3]);
    __syncthreads();
    double r = sbuf[0];
    __syncthreads();
    return r;
}

__device__ __forceinline__ unsigned short bf16rne(float f) {
    unsigned int u = __float_as_uint(f);
    unsigned int r = (u + 0x7FFFu + ((u >> 16) & 1u)) >> 16;
    return (unsigned short)r;
}

// monotone map float -> uint (order-preserving), and inverse
__device__ __forceinline__ unsigned int mapU(float f) {
    unsigned int u = __float_as_uint(f);
    return (u & 0x80000000u) ? ~u : (u | 0x80000000u);
}
__device__ __forceinline__ float unmapU(unsigned int m) {
    unsigned int u = (m & 0x80000000u) ? (m ^ 0x80000000u) : ~m;
    return __uint_as_float(u);
}

// ---------------- weight repack: dst[k*256 + o] = src[o*2304 + k] ----------------
__global__ void repack_w_kernel(const float* __restrict__ src, float* __restrict__ dst) {
    int k = blockIdx.x;      // 0..2303
    int o = threadIdx.x;     // 0..255
    dst[(size_t)k * 256 + o] = src[(size_t)o * 2304 + k];
}

// ---------------- codebook -> bf16 ----------------
__global__ void cbbf_kernel(const float* __restrict__ cb, unsigned short* __restrict__ cb_bf) {
    int i = blockIdx.x * 256 + threadIdx.x;   // 0..524287
    size_t base = (size_t)i * 4;
    float4 v = *(const float4*)(cb + base);
    short4v s;
    s[0] = (short)bf16rne(v.x);
    s[1] = (short)bf16rne(v.y);
    s[2] = (short)bf16rne(v.z);
    s[3] = (short)bf16rne(v.w);
    *(short4v*)(cb_bf + base) = s;
}

// ---------------- emb conv: z[B,C,H,W] -> ze[(b,h,w), e], f64-folded accumulation ----------------
__global__ __launch_bounds__(256) void conv_emb_kernel(const float* __restrict__ z,
                                                       const float* __restrict__ w1t,
                                                       const float* __restrict__ bias,
                                                       float* __restrict__ ze) {
    __shared__ float s[3 * 64 * 36];
    int bh = blockIdx.x;            // 0..511
    int b = bh >> 5, h = bh & 31;
    int e = threadIdx.x;
    double accd[32];
    #pragma unroll
    for (int w = 0; w < 32; ++w) accd[w] = 0.0;
    for (int i = threadIdx.x; i < 3 * 64 * 36; i += 256) s[i] = 0.f;
    __syncthreads();

    for (int cc = 0; cc < 256; cc += 64) {
        for (int i = threadIdx.x; i < 3 * 64 * 32; i += 256) {
            int r = i >> 11;
            int c = (i >> 5) & 63;
            int w = i & 31;
            int hh = h + r - 1;
            float v = 0.f;
            if (hh >= 0 && hh < 32) v = z[(size_t)b * 262144 + (size_t)(cc + c) * 1024 + hh * 32 + w];
            s[(r * 64 + c) * 36 + (w + 1)] = v;
        }
        __syncthreads();
        for (int c = 0; c < 64; ++c) {
            const float* wrow = w1t + (size_t)(cc + c) * 9 * 256 + e;
            float tmp[32];
            #pragma unroll
            for (int w = 0; w < 32; ++w) tmp[w] = 0.f;
            #pragma unroll
            for (int r = 0; r < 3; ++r) {
                float v[36];
                const float* lrow = s + (r * 64 + c) * 36;
                #pragma unroll
                for (int q = 0; q < 9; ++q) {
                    float4 t4 = *(const float4*)(lrow + q * 4);
                    v[q * 4 + 0] = t4.x; v[q * 4 + 1] = t4.y; v[q * 4 + 2] = t4.z; v[q * 4 + 3] = t4.w;
                }
                #pragma unroll
                for (int kw = 0; kw < 3; ++kw) {
                    float wv = wrow[(r * 3 + kw) * 256];
                    #pragma unroll
                    for (int w = 0; w < 32; ++w) tmp[w] = fmaf(v[w + kw], wv, tmp[w]);
                }
            }
            #pragma unroll
            for (int w = 0; w < 32; ++w) accd[w] += (double)tmp[w];
        }
        __syncthreads();
    }
    float bv = bias[e];
    int p0 = (b * 32 + h) * 32;
    #pragma unroll
    for (int w = 0; w < 32; ++w) ze[(size_t)(p0 + w) * 256 + e] = (float)accd[w] + bv;
}

// ---------------- layernorm: emits zf_bf16, snorm, mu, rstd ----------------
__global__ void ln_kernel(const float* __restrict__ ze, const float* __restrict__ g,
                          const float* __restrict__ bta, unsigned short* __restrict__ zfb,
                          float* __restrict__ snorm, float* __restrict__ mu_a,
                          float* __restrict__ r_a) {
    __shared__ double sbuf[4];
    int p = blockIdx.x; int t = threadIdx.x;
    float x = ze[(size_t)p * 256 + t];
    double sum = block_sum_d((double)x, sbuf);
    float mu = ((float)sum) / 256.0f;
    float dev = x - mu;
    float sq = dev * dev;
    double vs = block_sum_d((double)sq, sbuf);
    float var = ((float)vs) / 256.0f;
    float r = 1.0f / sqrtf(var + 1e-5f);
    float y = ((dev * r) * g[t]) + bta[t];
    zfb[(size_t)p * 256 + t] = bf16rne(y);
    float ysq = y * y;
    double ss = block_sum_d((double)ysq, sbuf);
    if (t == 0) { snorm[p] = (float)ss; mu_a[p] = mu; r_a[p] = r; }
}

// ---------------- bf16 MFMA screening GEMM ----------------
// PHASE 1: per-pixel max(dot~) via global atomicMax (uint-mapped)
// PHASE 2: emit candidates with dot~ >= gmax - SCREEN_T
template<int PHASE>
__global__ __launch_bounds__(256) void screen_gemm_kernel(const unsigned short* __restrict__ zf_bf,
                                                          const unsigned short* __restrict__ cb_bf,
                                                          unsigned int* __restrict__ gmax,
                                                          int* __restrict__ ccnt,
                                                          int* __restrict__ cand) {
    __shared__ short Bs[128 * 256];   // 64 KB, XOR-swizzled rows
    const int tid = threadIdx.x;
    const int wid = tid >> 6, lane = tid & 63;
    const int l15 = lane & 15, lg = lane >> 4;
    const int p0 = blockIdx.x * 64;
    const int nslice0 = blockIdx.y * 1024;

    // A fragments in registers: 4 m-frags x 8 k-steps
    short8 aF[4][8];
    #pragma unroll
    for (int mf = 0; mf < 4; ++mf)
        #pragma unroll
        for (int ks = 0; ks < 8; ++ks)
            aF[mf][ks] = *reinterpret_cast<const short8*>(
                zf_bf + (size_t)(p0 + mf * 16 + l15) * 256 + ks * 32 + lg * 8);

    float runmax[4][4];
    float thr[4][4];
    if (PHASE == 1) {
        #pragma unroll
        for (int mf = 0; mf < 4; ++mf)
            #pragma unroll
            for (int r = 0; r < 4; ++r) runmax[mf][r] = -3.4e38f;
    } else {
        #pragma unroll
        for (int mf = 0; mf < 4; ++mf)
            #pragma unroll
            for (int r = 0; r < 4; ++r)
                thr[mf][r] = unmapU(gmax[p0 + mf * 16 + lg * 4 + r]) - SCREEN_T;
    }

    const f32x4 zero4 = {0.f, 0.f, 0.f, 0.f};
    for (int it = 0; it < 8; ++it) {
        const int nb = nslice0 + it * 128;
        __syncthreads();
        // stage B tile 128 x 256 bf16 (4096 x 16B chunks)
        #pragma unroll
        for (int rnd = 0; rnd < 16; ++rnd) {
            int c = rnd * 256 + tid;
            int nr = c >> 5, c16 = c & 31;
            short8 v = *reinterpret_cast<const short8*>(cb_bf + (size_t)(nb + nr) * 256 + c16 * 8);
            int byt = (nr * 512 + c16 * 16) ^ ((nr & 7) << 4);
            *reinterpret_cast<short8*>((char*)Bs + byt) = v;
        }
        __syncthreads();

        f32x4 acc[4][2];
        #pragma unroll
        for (int mf = 0; mf < 4; ++mf) { acc[mf][0] = zero4; acc[mf][1] = zero4; }

        #pragma unroll
        for (int ks = 0; ks < 8; ++ks) {
            int nr0 = wid * 32 + l15;
            int nr1 = nr0 + 16;
            int b0o = (nr0 * 512 + ks * 64 + lg * 16) ^ ((nr0 & 7) << 4);
            int b1o = (nr1 * 512 + ks * 64 + lg * 16) ^ ((nr1 & 7) << 4);
            short8 b0 = *reinterpret_cast<const short8*>((char*)Bs + b0o);
            short8 b1 = *reinterpret_cast<const short8*>((char*)Bs + b1o);
            #pragma unroll
            for (int mf = 0; mf < 4; ++mf) {
                acc[mf][0] = __builtin_amdgcn_mfma_f32_16x16x32_bf16(aF[mf][ks], b0, acc[mf][0], 0, 0, 0);
                acc[mf][1] = __builtin_amdgcn_mfma_f32_16x16x32_bf16(aF[mf][ks], b1, acc[mf][1], 0, 0, 0);
            }
        }

        if (PHASE == 1) {
            #pragma unroll
            for (int mf = 0; mf < 4; ++mf)
                #pragma unroll
                for (int r = 0; r < 4; ++r)
                    runmax[mf][r] = fmaxf(runmax[mf][r], fmaxf(acc[mf][0][r], acc[mf][1][r]));
        } else {
            #pragma unroll
            for (int mf = 0; mf < 4; ++mf) {
                #pragma unroll
                for (int nf = 0; nf < 2; ++nf) {
                    int ncol = nb + wid * 32 + nf * 16 + l15;
                    #pragma unroll
                    for (int r = 0; r < 4; ++r) {
                        if (acc[mf][nf][r] >= thr[mf][r]) {
                            int p = p0 + mf * 16 + lg * 4 + r;
                            int slot = atomicAdd(&ccnt[p], 1);
                            if (slot < CAND_SLOTS) cand[(size_t)p * CAND_SLOTS + slot] = ncol;
                        }
                    }
                }
            }
        }
    }

    if (PHASE == 1) {
        #pragma unroll
        for (int mf = 0; mf < 4; ++mf)
            #pragma unroll
            for (int r = 0; r < 4; ++r) {
                float v = runmax[mf][r];
                #pragma unroll
                for (int s = 1; s < 16; s <<= 1) v = fmaxf(v, __shfl_xor(v, s, 64));
                if (l15 == 0) atomicMax(&gmax[p0 + mf * 16 + lg * 4 + r], mapU(v));
            }
    }
}

// ---------------- exact rescore (bit-identical to round-2 dist arithmetic) ----------------
__global__ __launch_bounds__(256) void rescore_kernel(const float* __restrict__ ze,
                                                      const float* __restrict__ mu_a,
                                                      const float* __restrict__ r_a,
                                                      const float* __restrict__ snorm,
                                                      const float* __restrict__ g,
                                                      const float* __restrict__ bta,
                                                      const float* __restrict__ cb,
                                                      const int* __restrict__ ccnt,
                                                      const int* __restrict__ cand,
                                                      int* __restrict__ idx_i,
                                                      float* __restrict__ idx_f) {
    int p = blockIdx.x * 4 + (threadIdx.x >> 6);
    int lane = threadIdx.x & 63;
    int cnt = ccnt[p];
    if (cnt > CAND_SLOTS) cnt = CAND_SLOTS;
    float d = 3.4e38f;
    int ix = 0x7FFFFFFF;
    if (lane < cnt) {
        int n = cand[(size_t)p * CAND_SLOTS + lane];
        float mu = mu_a[p];
        float r = r_a[p];
        const float* zr = ze + (size_t)p * 256;
        const float* cr = cb + (size_t)n * 256;
        float a0 = 0.f, a1 = 0.f, a2 = 0.f, a3 = 0.f;
        for (int k0 = 0; k0 < 256; k0 += 4) {
            float4 zq = *(const float4*)(zr + k0);
            float4 gq = *(const float4*)(g + k0);
            float4 bq = *(const float4*)(bta + k0);
            float4 cq = *(const float4*)(cr + k0);
            float d0 = zq.x - mu; float y0 = ((d0 * r) * gq.x) + bq.x;
            float d1 = zq.y - mu; float y1 = ((d1 * r) * gq.y) + bq.y;
            float d2 = zq.z - mu; float y2 = ((d2 * r) * gq.z) + bq.z;
            float d3 = zq.w - mu; float y3 = ((d3 * r) * gq.w) + bq.w;
            a0 = fmaf(y0, cq.x, a0);
            a1 = fmaf(y1, cq.y, a1);
            a2 = fmaf(y2, cq.z, a2);
            a3 = fmaf(y3, cq.w, a3);
        }
        float dot32 = (float)(((double)a0 + (double)a1) + ((double)a2 + (double)a3));
        d = fmaf(-2.0f, dot32, snorm[p]);
        ix = n;
    }
    #pragma unroll
    for (int off = 32; off > 0; off >>= 1) {
        float ov = __shfl_down(d, off, 64);
        int   oi = __shfl_down(ix, off, 64);
        if (ov < d || (ov == d && oi < ix)) { d = ov; ix = oi; }
    }
    if (lane == 0) {
        idx_i[p] = ix;
        idx_f[p] = (float)ix;
    }
}

// ---------------- loss ----------------
__global__ void loss_partial_kernel(const float* __restrict__ ze, const float* __restrict__ cb,
                                    const int* __restrict__ idx, float* __restrict__ partials) {
    __shared__ float sbuf[4];
    float sum = 0.f;
    const int total = NPIX * 256;
    for (int i = blockIdx.x * blockDim.x + threadIdx.x; i < total; i += gridDim.x * blockDim.x) {
        int p = i >> 8;
        int e = i & 255;
        float d = cb[(size_t)idx[p] * 256 + e] - ze[i];
        sum = fmaf(d, d, sum);
    }
    sum = block_sum(sum, sbuf);
    if (threadIdx.x == 0) partials[blockIdx.x] = sum;
}

__global__ void loss_final_kernel(const float* __restrict__ partials, float* __restrict__ loss_out) {
    __shared__ float sbuf[4];
    float v = partials[threadIdx.x];
    v = block_sum(v, sbuf);
    if (threadIdx.x == 0) *loss_out = v * (1.25f / (float)(NPIX * 256));
}

// ---------------- unemb conv ----------------
__global__ __launch_bounds__(256) void conv_unemb_kernel(const float* __restrict__ cb,
                                                         const int* __restrict__ idx,
                                                         const float* __restrict__ w2t,
                                                         const float* __restrict__ bias,
                                                         float* __restrict__ out) {
    __shared__ float s[3 * 64 * 36];
    int bh = blockIdx.x;
    int b = bh >> 5, h = bh & 31;
    int cth = threadIdx.x;
    float acc[32];
    #pragma unroll
    for (int w = 0; w < 32; ++w) acc[w] = 0.f;
    for (int i = threadIdx.x; i < 3 * 64 * 36; i += 256) s[i] = 0.f;
    __syncthreads();

    for (int cc = 0; cc < 256; cc += 64) {
        for (int i = threadIdx.x; i < 3 * 32 * 64; i += 256) {
            int r = i >> 11;
            int w = (i >> 6) & 31;
            int ee = i & 63;
            int hh = h + r - 1;
            float v = 0.f;
            if (hh >= 0 && hh < 32) {
                int p = (b * 32 + hh) * 32 + w;
                v = cb[(size_t)idx[p] * 256 + cc + ee];
            }
            s[(r * 64 + ee) * 36 + (w + 1)] = v;
        }
        __syncthreads();
        for (int ee = 0; ee < 64; ++ee) {
            const float* wrow = w2t + (size_t)(cc + ee) * 9 * 256 + cth;
            #pragma unroll
            for (int r = 0; r < 3; ++r) {
                float v[36];
                const float* lrow = s + (r * 64 + ee) * 36;
                #pragma unroll
                for (int q = 0; q < 9; ++q) {
                    float4 t4 = *(const float4*)(lrow + q * 4);
                    v[q * 4 + 0] = t4.x; v[q * 4 + 1] = t4.y; v[q * 4 + 2] = t4.z; v[q * 4 + 3] = t4.w;
                }
                #pragma unroll
                for (int kw = 0; kw < 3; ++kw) {
                    float wv = wrow[(r * 3 + kw) * 256];
                    #pragma unroll
                    for (int w = 0; w < 32; ++w) acc[w] = fmaf(v[w + kw], wv, acc[w]);
                }
            }
        }
        __syncthreads();
    }
    float bv = bias[cth];
    float* orow = out + ((size_t)(b * 256 + cth) * 32 + h) * 32;
    #pragma unroll
    for (int w = 0; w < 32; ++w) orow[w] = acc[w] + bv;
}

extern "C" void kernel_launch(void* const* d_in, const int* in_sizes, int n_in,
                              void* d_out, int out_size, void* d_ws, size_t ws_size,
                              hipStream_t stream) {
    const float* z       = (const float*)d_in[0];
    const float* emb_w   = (const float*)d_in[1];
    const float* emb_b   = (const float*)d_in[2];
    const float* ln_g    = (const float*)d_in[3];
    const float* ln_b    = (const float*)d_in[4];
    const float* cb      = (const float*)d_in[5];
    const float* unemb_w = (const float*)d_in[6];
    const float* unemb_b = (const float*)d_in[7];

    float* out    = (float*)d_out;                    // [16,256,32,32]
    float* lossp  = out + OUT_ELEMS;                  // scalar
    float* idxf   = out + OUT_ELEMS + 1;              // [16384] as float

    // workspace layout (float slots)
    float* ws = (float*)d_ws;
    float* ze_t = ws;                                          // 4,194,304
    unsigned short* zf_bf = (unsigned short*)(ze_t + (size_t)NPIX * 256);   // 2,097,152 fl slots
    unsigned short* cb_bf = (unsigned short*)((float*)zf_bf + 2097152);     // 1,048,576 fl slots
    float* snorm = (float*)cb_bf + 1048576;                    // 16,384
    float* mu_a  = snorm + NPIX;                               // 16,384
    float* r_a   = mu_a + NPIX;                                // 16,384
    float* w1t   = r_a + NPIX;                                 // 589,824
    float* w2t   = w1t + 2304 * 256;                           // 589,824
    unsigned int* gmax = (unsigned int*)(w2t + 2304 * 256);    // 16,384
    int*   ccnt  = (int*)(gmax + NPIX);                        // 16,384
    int*   cand  = ccnt + NPIX;                                // 524,288
    int*   idxi  = cand + (size_t)NPIX * CAND_SLOTS;           // 16,384
    float* partials = (float*)(idxi + NPIX);                   // 256

    hipLaunchKernelGGL(repack_w_kernel, dim3(2304), dim3(256), 0, stream, emb_w, w1t);
    hipLaunchKernelGGL(repack_w_kernel, dim3(2304), dim3(256), 0, stream, unemb_w, w2t);
    hipLaunchKernelGGL(cbbf_kernel, dim3(2048), dim3(256), 0, stream, cb, cb_bf);
    hipLaunchKernelGGL(conv_emb_kernel, dim3(512), dim3(256), 0, stream, z, w1t, emb_b, ze_t);
    hipLaunchKernelGGL(ln_kernel, dim3(NPIX), dim3(256), 0, stream, ze_t, ln_g, ln_b,
                       zf_bf, snorm, mu_a, r_a);
    hipMemsetAsync(gmax, 0, NPIX * sizeof(unsigned int), stream);
    hipMemsetAsync(ccnt, 0, NPIX * sizeof(int), stream);
    hipLaunchKernelGGL((screen_gemm_kernel<1>), dim3(256, 8), dim3(256), 0, stream,
                       zf_bf, cb_bf, gmax, ccnt, cand);
    hipLaunchKernelGGL((screen_gemm_kernel<2>), dim3(256, 8), dim3(256), 0, stream,
                       zf_bf, cb_bf, gmax, ccnt, cand);
    hipLaunchKernelGGL(rescore_kernel, dim3(NPIX / 4), dim3(256), 0, stream,
                       ze_t, mu_a, r_a, snorm, ln_g, ln_b, cb, ccnt, cand, idxi, idxf);
    hipLaunchKernelGGL(loss_partial_kernel, dim3(256), dim3(256), 0, stream, ze_t, cb, idxi, partials);
    hipLaunchKernelGGL(loss_final_kernel, dim3(1), dim3(256), 0, stream, partials, lossp);
    hipLaunchKernelGGL(conv_unemb_kernel, dim3(512), dim3(256), 0, stream, cb, idxi, w2t, unemb_b, out);
}

// Round 4
// 1146.465 us; speedup vs baseline: 3.0915x; 1.3303x over previous
//
#include <hip/hip_runtime.h>
#include <hip/hip_bf16.h>

#define B_SZ 16
#define CIN 256
#define EDIM 256
#define NE 8192
#define HW 32
#define NPIX (B_SZ*HW*HW)          // 16384
#define OUT_ELEMS (B_SZ*CIN*HW*HW) // 4194304
#define SCREEN_T 3.2e-4f
#define CAND_SLOTS 32

typedef __attribute__((ext_vector_type(8))) short short8;
typedef __attribute__((ext_vector_type(4))) short short4v;
typedef __attribute__((ext_vector_type(4))) float f32x4;

// ---------------- helpers ----------------
__device__ __forceinline__ float block_sum(float v, float* sbuf) {
    #pragma unroll
    for (int off = 32; off > 0; off >>= 1) v += __shfl_down(v, off, 64);
    int wid = threadIdx.x >> 6;
    int lane = threadIdx.x & 63;
    if (lane == 0) sbuf[wid] = v;
    __syncthreads();
    if (threadIdx.x == 0) sbuf[0] = sbuf[0] + sbuf[1] + sbuf[2] + sbuf[3];
    __syncthreads();
    float r = sbuf[0];
    __syncthreads();
    return r;
}

__device__ __forceinline__ double block_sum_d(double v, double* sbuf) {
    #pragma unroll
    for (int off = 32; off > 0; off >>= 1) v += __shfl_down(v, off, 64);
    int wid = threadIdx.x >> 6;
    int lane = threadIdx.x & 63;
    if (lane == 0) sbuf[wid] = v;
    __syncthreads();
    if (threadIdx.x == 0) sbuf[0] = (sbuf[0] + sbuf[1]) + (sbuf[2] + sbuf[3]);
    __syncthreads();
    double r = sbuf[0];
    __syncthreads();
    return r;
}

__device__ __forceinline__ unsigned short bf16rne(float f) {
    unsigned int u = __float_as_uint(f);
    unsigned int r = (u + 0x7FFFu + ((u >> 16) & 1u)) >> 16;
    return (unsigned short)r;
}
__device__ __forceinline__ float bf2f(unsigned short h) {
    return __uint_as_float((unsigned int)h << 16);
}

// monotone map float -> uint (order-preserving), and inverse
__device__ __forceinline__ unsigned int mapU(float f) {
    unsigned int u = __float_as_uint(f);
    return (u & 0x80000000u) ? ~u : (u | 0x80000000u);
}
__device__ __forceinline__ float unmapU(unsigned int m) {
    unsigned int u = (m & 0x80000000u) ? (m ^ 0x80000000u) : ~m;
    return __uint_as_float(u);
}

// ---------------- weight repack: dst[k*256 + o] = src[o*2304 + k] ----------------
__global__ void repack_w_kernel(const float* __restrict__ src, float* __restrict__ dst) {
    int k = blockIdx.x;      // 0..2303
    int o = threadIdx.x;     // 0..255
    dst[(size_t)k * 256 + o] = src[(size_t)o * 2304 + k];
}

// ---------------- unemb weights -> bf16 hi/lo, tap-major: d[cout][tap*256+e] ----------------
__global__ void w2bf_kernel(const float* __restrict__ src, unsigned short* __restrict__ dhi,
                            unsigned short* __restrict__ dlo) {
    int blk = blockIdx.x;        // cout*9 + tap
    int cout = blk / 9, tap = blk % 9;
    int e = threadIdx.x;
    float v = src[(size_t)cout * 2304 + e * 9 + tap];
    unsigned short h = bf16rne(v);
    unsigned short l = bf16rne(v - bf2f(h));
    size_t j = (size_t)cout * 2304 + tap * 256 + e;
    dhi[j] = h; dlo[j] = l;
}

// ---------------- codebook -> bf16 hi/lo ----------------
__global__ void cbbf_kernel(const float* __restrict__ cb, unsigned short* __restrict__ cb_hi,
                            unsigned short* __restrict__ cb_lo) {
    int i = blockIdx.x * 256 + threadIdx.x;   // 0..524287
    size_t base = (size_t)i * 4;
    float4 v = *(const float4*)(cb + base);
    short4v sh, sl;
    unsigned short h;
    h = bf16rne(v.x); sh[0] = (short)h; sl[0] = (short)bf16rne(v.x - bf2f(h));
    h = bf16rne(v.y); sh[1] = (short)h; sl[1] = (short)bf16rne(v.y - bf2f(h));
    h = bf16rne(v.z); sh[2] = (short)h; sl[2] = (short)bf16rne(v.z - bf2f(h));
    h = bf16rne(v.w); sh[3] = (short)h; sl[3] = (short)bf16rne(v.w - bf2f(h));
    *(short4v*)(cb_hi + base) = sh;
    *(short4v*)(cb_lo + base) = sl;
}

// ---------------- emb conv: z[B,C,H,W] -> ze[(b,h,w), e] ----------------
// Bit-exact same per-output arithmetic as round-2/3 (9-FMA chain per c, f64 fold per c),
// restructured: grid (512 bh x 2 cout-halves), thread = (e 0..127, w-half).
__global__ __launch_bounds__(256, 4) void conv_emb_kernel(const float* __restrict__ z,
                                                          const float* __restrict__ w1t,
                                                          const float* __restrict__ bias,
                                                          float* __restrict__ ze) {
    __shared__ float s[3 * 64 * 36];
    int bh = blockIdx.x;            // 0..511
    int b = bh >> 5, h = bh & 31;
    int e = (blockIdx.y << 7) + (threadIdx.x & 127);
    int wh = threadIdx.x >> 7;      // 0..1
    double accd[16];
    #pragma unroll
    for (int i = 0; i < 16; ++i) accd[i] = 0.0;
    for (int i = threadIdx.x; i < 3 * 64 * 36; i += 256) s[i] = 0.f;
    __syncthreads();

    for (int cc = 0; cc < 256; cc += 64) {
        for (int i = threadIdx.x; i < 3 * 64 * 32; i += 256) {
            int r = i >> 11;
            int c = (i >> 5) & 63;
            int w = i & 31;
            int hh = h + r - 1;
            float v = 0.f;
            if (hh >= 0 && hh < 32) v = z[(size_t)b * 262144 + (size_t)(cc + c) * 1024 + hh * 32 + w];
            s[(r * 64 + c) * 36 + (w + 1)] = v;
        }
        __syncthreads();
        for (int c = 0; c < 64; ++c) {
            const float* wrow = w1t + (size_t)(cc + c) * 9 * 256 + e;
            float tmp[16];
            #pragma unroll
            for (int i = 0; i < 16; ++i) tmp[i] = 0.f;
            #pragma unroll
            for (int r = 0; r < 3; ++r) {
                float v[20];
                const float* lrow = s + (r * 64 + c) * 36 + wh * 16;
                #pragma unroll
                for (int q = 0; q < 5; ++q) {
                    float4 t4 = *(const float4*)(lrow + q * 4);
                    v[q * 4 + 0] = t4.x; v[q * 4 + 1] = t4.y; v[q * 4 + 2] = t4.z; v[q * 4 + 3] = t4.w;
                }
                #pragma unroll
                for (int kw = 0; kw < 3; ++kw) {
                    float wv = wrow[(r * 3 + kw) * 256];
                    #pragma unroll
                    for (int i = 0; i < 16; ++i) tmp[i] = fmaf(v[i + kw], wv, tmp[i]);
                }
            }
            #pragma unroll
            for (int i = 0; i < 16; ++i) accd[i] += (double)tmp[i];
        }
        __syncthreads();
    }
    float bv = bias[e];
    int p0 = (b * 32 + h) * 32 + wh * 16;
    #pragma unroll
    for (int i = 0; i < 16; ++i) ze[(size_t)(p0 + i) * 256 + e] = (float)accd[i] + bv;
}

// ---------------- layernorm: emits zf_bf16, snorm, mu, rstd ----------------
__global__ void ln_kernel(const float* __restrict__ ze, const float* __restrict__ g,
                          const float* __restrict__ bta, unsigned short* __restrict__ zfb,
                          float* __restrict__ snorm, float* __restrict__ mu_a,
                          float* __restrict__ r_a) {
    __shared__ double sbuf[4];
    int p = blockIdx.x; int t = threadIdx.x;
    float x = ze[(size_t)p * 256 + t];
    double sum = block_sum_d((double)x, sbuf);
    float mu = ((float)sum) / 256.0f;
    float dev = x - mu;
    float sq = dev * dev;
    double vs = block_sum_d((double)sq, sbuf);
    float var = ((float)vs) / 256.0f;
    float r = 1.0f / sqrtf(var + 1e-5f);
    float y = ((dev * r) * g[t]) + bta[t];
    zfb[(size_t)p * 256 + t] = bf16rne(y);
    float ysq = y * y;
    double ss = block_sum_d((double)ysq, sbuf);
    if (t == 0) { snorm[p] = (float)ss; mu_a[p] = mu; r_a[p] = r; }
}

// ---------------- bf16 MFMA screening GEMM ----------------
template<int PHASE>
__global__ __launch_bounds__(256) void screen_gemm_kernel(const unsigned short* __restrict__ zf_bf,
                                                          const unsigned short* __restrict__ cb_bf,
                                                          unsigned int* __restrict__ gmax,
                                                          int* __restrict__ ccnt,
                                                          int* __restrict__ cand) {
    __shared__ short Bs[128 * 256];   // 64 KB, XOR-swizzled rows
    const int tid = threadIdx.x;
    const int wid = tid >> 6, lane = tid & 63;
    const int l15 = lane & 15, lg = lane >> 4;
    const int p0 = blockIdx.x * 64;
    const int nslice0 = blockIdx.y * 1024;

    short8 aF[4][8];
    #pragma unroll
    for (int mf = 0; mf < 4; ++mf)
        #pragma unroll
        for (int ks = 0; ks < 8; ++ks)
            aF[mf][ks] = *reinterpret_cast<const short8*>(
                zf_bf + (size_t)(p0 + mf * 16 + l15) * 256 + ks * 32 + lg * 8);

    float runmax[4][4];
    float thr[4][4];
    if (PHASE == 1) {
        #pragma unroll
        for (int mf = 0; mf < 4; ++mf)
            #pragma unroll
            for (int r = 0; r < 4; ++r) runmax[mf][r] = -3.4e38f;
    } else {
        #pragma unroll
        for (int mf = 0; mf < 4; ++mf)
            #pragma unroll
            for (int r = 0; r < 4; ++r)
                thr[mf][r] = unmapU(gmax[p0 + mf * 16 + lg * 4 + r]) - SCREEN_T;
    }

    const f32x4 zero4 = {0.f, 0.f, 0.f, 0.f};
    for (int it = 0; it < 8; ++it) {
        const int nb = nslice0 + it * 128;
        __syncthreads();
        #pragma unroll
        for (int rnd = 0; rnd < 16; ++rnd) {
            int c = rnd * 256 + tid;
            int nr = c >> 5, c16 = c & 31;
            short8 v = *reinterpret_cast<const short8*>(cb_bf + (size_t)(nb + nr) * 256 + c16 * 8);
            int byt = (nr * 512 + c16 * 16) ^ ((nr & 7) << 4);
            *reinterpret_cast<short8*>((char*)Bs + byt) = v;
        }
        __syncthreads();

        f32x4 acc[4][2];
        #pragma unroll
        for (int mf = 0; mf < 4; ++mf) { acc[mf][0] = zero4; acc[mf][1] = zero4; }

        #pragma unroll
        for (int ks = 0; ks < 8; ++ks) {
            int nr0 = wid * 32 + l15;
            int nr1 = nr0 + 16;
            int b0o = (nr0 * 512 + ks * 64 + lg * 16) ^ ((nr0 & 7) << 4);
            int b1o = (nr1 * 512 + ks * 64 + lg * 16) ^ ((nr1 & 7) << 4);
            short8 b0 = *reinterpret_cast<const short8*>((char*)Bs + b0o);
            short8 b1 = *reinterpret_cast<const short8*>((char*)Bs + b1o);
            #pragma unroll
            for (int mf = 0; mf < 4; ++mf) {
                acc[mf][0] = __builtin_amdgcn_mfma_f32_16x16x32_bf16(aF[mf][ks], b0, acc[mf][0], 0, 0, 0);
                acc[mf][1] = __builtin_amdgcn_mfma_f32_16x16x32_bf16(aF[mf][ks], b1, acc[mf][1], 0, 0, 0);
            }
        }

        if (PHASE == 1) {
            #pragma unroll
            for (int mf = 0; mf < 4; ++mf)
                #pragma unroll
                for (int r = 0; r < 4; ++r)
                    runmax[mf][r] = fmaxf(runmax[mf][r], fmaxf(acc[mf][0][r], acc[mf][1][r]));
        } else {
            #pragma unroll
            for (int mf = 0; mf < 4; ++mf) {
                #pragma unroll
                for (int nf = 0; nf < 2; ++nf) {
                    int ncol = nb + wid * 32 + nf * 16 + l15;
                    #pragma unroll
                    for (int r = 0; r < 4; ++r) {
                        if (acc[mf][nf][r] >= thr[mf][r]) {
                            int p = p0 + mf * 16 + lg * 4 + r;
                            int slot = atomicAdd(&ccnt[p], 1);
                            if (slot < CAND_SLOTS) cand[(size_t)p * CAND_SLOTS + slot] = ncol;
                        }
                    }
                }
            }
        }
    }

    if (PHASE == 1) {
        #pragma unroll
        for (int mf = 0; mf < 4; ++mf)
            #pragma unroll
            for (int r = 0; r < 4; ++r) {
                float v = runmax[mf][r];
                #pragma unroll
                for (int s = 1; s < 16; s <<= 1) v = fmaxf(v, __shfl_xor(v, s, 64));
                if (l15 == 0) atomicMax(&gmax[p0 + mf * 16 + lg * 4 + r], mapU(v));
            }
    }
}

// ---------------- exact rescore (bit-identical to round-2 dist arithmetic) ----------------
__global__ __launch_bounds__(256) void rescore_kernel(const float* __restrict__ ze,
                                                      const float* __restrict__ mu_a,
                                                      const float* __restrict__ r_a,
                                                      const float* __restrict__ snorm,
                                                      const float* __restrict__ g,
                                                      const float* __restrict__ bta,
                                                      const float* __restrict__ cb,
                                                      const int* __restrict__ ccnt,
                                                      const int* __restrict__ cand,
                                                      int* __restrict__ idx_i,
                                                      float* __restrict__ idx_f) {
    int p = blockIdx.x * 4 + (threadIdx.x >> 6);
    int lane = threadIdx.x & 63;
    int cnt = ccnt[p];
    if (cnt > CAND_SLOTS) cnt = CAND_SLOTS;
    float d = 3.4e38f;
    int ix = 0x7FFFFFFF;
    if (lane < cnt) {
        int n = cand[(size_t)p * CAND_SLOTS + lane];
        float mu = mu_a[p];
        float r = r_a[p];
        const float* zr = ze + (size_t)p * 256;
        const float* cr = cb + (size_t)n * 256;
        float a0 = 0.f, a1 = 0.f, a2 = 0.f, a3 = 0.f;
        for (int k0 = 0; k0 < 256; k0 += 4) {
            float4 zq = *(const float4*)(zr + k0);
            float4 gq = *(const float4*)(g + k0);
            float4 bq = *(const float4*)(bta + k0);
            float4 cq = *(const float4*)(cr + k0);
            float d0 = zq.x - mu; float y0 = ((d0 * r) * gq.x) + bq.x;
            float d1 = zq.y - mu; float y1 = ((d1 * r) * gq.y) + bq.y;
            float d2 = zq.z - mu; float y2 = ((d2 * r) * gq.z) + bq.z;
            float d3 = zq.w - mu; float y3 = ((d3 * r) * gq.w) + bq.w;
            a0 = fmaf(y0, cq.x, a0);
            a1 = fmaf(y1, cq.y, a1);
            a2 = fmaf(y2, cq.z, a2);
            a3 = fmaf(y3, cq.w, a3);
        }
        float dot32 = (float)(((double)a0 + (double)a1) + ((double)a2 + (double)a3));
        d = fmaf(-2.0f, dot32, snorm[p]);
        ix = n;
    }
    #pragma unroll
    for (int off = 32; off > 0; off >>= 1) {
        float ov = __shfl_down(d, off, 64);
        int   oi = __shfl_down(ix, off, 64);
        if (ov < d || (ov == d && oi < ix)) { d = ov; ix = oi; }
    }
    if (lane == 0) {
        idx_i[p] = ix;
        idx_f[p] = (float)ix;
    }
}

// ---------------- loss ----------------
__global__ void loss_partial_kernel(const float* __restrict__ ze, const float* __restrict__ cb,
                                    const int* __restrict__ idx, float* __restrict__ partials) {
    __shared__ float sbuf[4];
    float sum = 0.f;
    const int total = NPIX * 256;
    for (int i = blockIdx.x * blockDim.x + threadIdx.x; i < total; i += gridDim.x * blockDim.x) {
        int p = i >> 8;
        int e = i & 255;
        float d = cb[(size_t)idx[p] * 256 + e] - ze[i];
        sum = fmaf(d, d, sum);
    }
    sum = block_sum(sum, sbuf);
    if (threadIdx.x == 0) partials[blockIdx.x] = sum;
}

__global__ void loss_final_kernel(const float* __restrict__ partials, float* __restrict__ loss_out) {
    __shared__ float sbuf[4];
    float v = partials[threadIdx.x];
    v = block_sum(v, sbuf);
    if (threadIdx.x == 0) *loss_out = v * (1.25f / (float)(NPIX * 256));
}

// ---------------- unemb conv as split-bf16 MFMA implicit GEMM ----------------
// block = (b,h) row: 32 pixels x 128 couts (blockIdx.y = cout half). 4 waves.
// A (hi/lo) staged per e-chunk in LDS with XOR-16B swizzle; B loaded from global (L2-hot).
#define AROWB 128                      // bytes per A row (64 bf16)
#define ALO   13056                    // offset of lo split: 3*34*128
__global__ __launch_bounds__(256, 4) void conv_unemb_mfma(const unsigned short* __restrict__ cb_hi,
                                                          const unsigned short* __restrict__ cb_lo,
                                                          const int* __restrict__ idx,
                                                          const unsigned short* __restrict__ w2_hi,
                                                          const unsigned short* __restrict__ w2_lo,
                                                          const float* __restrict__ bias,
                                                          float* __restrict__ out) {
    __shared__ char smem[2 * ALO];     // 26112 B; reused as ot[128][36] f32 for epilogue
    float* ot = (float*)smem;
    const int tid = threadIdx.x;
    const int wid = tid >> 6, lane = tid & 63;
    const int l15 = lane & 15, lg = lane >> 4;
    const int bh = blockIdx.x;
    const int b = bh >> 5, h = bh & 31;
    const int ch = blockIdx.y;         // cout half

    // zero A region (pads + out-of-range h rows stay zero forever)
    for (int i = tid; i < (2 * ALO) / 16; i += 256) ((int4*)smem)[i] = make_int4(0, 0, 0, 0);

    // per-thread staging assignment (3 rounds x 8 e-threads per row)
    int nrow[3], rok[3], wpos[3], rr3[3];
    #pragma unroll
    for (int rd = 0; rd < 3; ++rd) {
        int t2 = rd * 256 + tid;
        int row = t2 >> 3;             // 0..95
        int r = row >> 5, w = row & 31;
        int hh = h + r - 1;
        rok[rd] = (hh >= 0 && hh < 32) ? 1 : 0;
        rr3[rd] = r; wpos[rd] = w;
        nrow[rd] = rok[rd] ? idx[(b * 32 + hh) * 32 + w] : 0;
    }
    __syncthreads();

    const f32x4 zero4 = {0.f, 0.f, 0.f, 0.f};
    f32x4 acc[2][2];
    acc[0][0] = zero4; acc[0][1] = zero4; acc[1][0] = zero4; acc[1][1] = zero4;

    for (int ec = 0; ec < 4; ++ec) {
        if (ec) __syncthreads();
        // stage A hi/lo for this e-chunk
        #pragma unroll
        for (int rd = 0; rd < 3; ++rd) {
            if (rok[rd]) {
                int t2 = rd * 256 + tid;
                int eo = (t2 & 7) * 8;
                size_t gsrc = (size_t)nrow[rd] * 256 + ec * 64 + eo;
                short8 vh = *(const short8*)(cb_hi + gsrc);
                short8 vl = *(const short8*)(cb_lo + gsrc);
                int wp = wpos[rd] + 1;
                int rowbase = (rr3[rd] * 34 + wp) * AROWB;
                int boff = (eo * 2) ^ ((wp & 7) << 4);
                *(short8*)(smem + rowbase + boff) = vh;
                *(short8*)(smem + ALO + rowbase + boff) = vl;
            }
        }
        __syncthreads();

        #pragma unroll
        for (int tap = 0; tap < 9; ++tap) {
            const int r = tap / 3, kw = tap % 3;
            #pragma unroll
            for (int ks = 0; ks < 2; ++ks) {
                int e2 = ks * 32 + lg * 8;
                short8 ah[2], al[2], bh2[2], bl2[2];
                #pragma unroll
                for (int mf = 0; mf < 2; ++mf) {
                    int wp = mf * 16 + l15 + kw;              // 0..33
                    int rowbase = (r * 34 + wp) * AROWB;
                    int boff = (e2 * 2) ^ ((wp & 7) << 4);
                    ah[mf] = *(const short8*)(smem + rowbase + boff);
                    al[mf] = *(const short8*)(smem + ALO + rowbase + boff);
                }
                #pragma unroll
                for (int nf = 0; nf < 2; ++nf) {
                    int cout = (ch << 7) + (wid << 5) + (nf << 4) + l15;
                    size_t goff = (size_t)cout * 2304 + tap * 256 + ec * 64 + e2;
                    bh2[nf] = *(const short8*)(w2_hi + goff);
                    bl2[nf] = *(const short8*)(w2_lo + goff);
                }
                #pragma unroll
                for (int mf = 0; mf < 2; ++mf)
                    #pragma unroll
                    for (int nf = 0; nf < 2; ++nf) {
                        acc[mf][nf] = __builtin_amdgcn_mfma_f32_16x16x32_bf16(ah[mf], bh2[nf], acc[mf][nf], 0, 0, 0);
                        acc[mf][nf] = __builtin_amdgcn_mfma_f32_16x16x32_bf16(ah[mf], bl2[nf], acc[mf][nf], 0, 0, 0);
                        acc[mf][nf] = __builtin_amdgcn_mfma_f32_16x16x32_bf16(al[mf], bh2[nf], acc[mf][nf], 0, 0, 0);
                    }
            }
        }
    }
    __syncthreads();
    // transpose through LDS: ot[cout_local][pixel], rows padded to 36
    #pragma unroll
    for (int mf = 0; mf < 2; ++mf)
        #pragma unroll
        for (int nf = 0; nf < 2; ++nf) {
            int cl = (wid << 5) + (nf << 4) + l15;
            #pragma unroll
            for (int rr = 0; rr < 4; ++rr) {
                int px = mf * 16 + lg * 4 + rr;
                ot[cl * 36 + px] = acc[mf][nf][rr];
            }
        }
    __syncthreads();
    int row = tid >> 1, half = tid & 1;
    int cout = (ch << 7) + row;
    float bv = bias[cout];
    float* dst = out + ((size_t)(b * 256 + cout) * 32 + h) * 32 + half * 16;
    const float* src = ot + row * 36 + half * 16;
    #pragma unroll
    for (int q = 0; q < 4; ++q) {
        float4 v = *(const float4*)(src + q * 4);
        v.x += bv; v.y += bv; v.z += bv; v.w += bv;
        *(float4*)(dst + q * 4) = v;
    }
}

extern "C" void kernel_launch(void* const* d_in, const int* in_sizes, int n_in,
                              void* d_out, int out_size, void* d_ws, size_t ws_size,
                              hipStream_t stream) {
    const float* z       = (const float*)d_in[0];
    const float* emb_w   = (const float*)d_in[1];
    const float* emb_b   = (const float*)d_in[2];
    const float* ln_g    = (const float*)d_in[3];
    const float* ln_b    = (const float*)d_in[4];
    const float* cb      = (const float*)d_in[5];
    const float* unemb_w = (const float*)d_in[6];
    const float* unemb_b = (const float*)d_in[7];

    float* out    = (float*)d_out;                    // [16,256,32,32]
    float* lossp  = out + OUT_ELEMS;                  // scalar
    float* idxf   = out + OUT_ELEMS + 1;              // [16384] as float

    // workspace layout (float slots), total ~10.2M floats (~41 MB)
    float* ws = (float*)d_ws;
    float* ze_t = ws;                                               // 4,194,304
    unsigned short* zf_bf = (unsigned short*)(ze_t + (size_t)NPIX * 256);      // 2,097,152 fl
    unsigned short* cb_hi = (unsigned short*)((float*)zf_bf + 2097152);        // 1,048,576 fl
    unsigned short* cb_lo = (unsigned short*)((float*)cb_hi + 1048576);        // 1,048,576 fl
    float* snorm = (float*)cb_lo + 1048576;                         // 16,384
    float* mu_a  = snorm + NPIX;                                    // 16,384
    float* r_a   = mu_a + NPIX;                                     // 16,384
    float* w1t   = r_a + NPIX;                                      // 589,824
    unsigned short* w2_hi = (unsigned short*)(w1t + 2304 * 256);    // 294,912 fl
    unsigned short* w2_lo = (unsigned short*)((float*)w2_hi + 294912); // 294,912 fl
    unsigned int* gmax = (unsigned int*)((float*)w2_lo + 294912);   // 16,384
    int*   ccnt  = (int*)(gmax + NPIX);                             // 16,384
    int*   cand  = ccnt + NPIX;                                     // 524,288
    int*   idxi  = cand + (size_t)NPIX * CAND_SLOTS;                // 16,384
    float* partials = (float*)(idxi + NPIX);                        // 256

    hipLaunchKernelGGL(repack_w_kernel, dim3(2304), dim3(256), 0, stream, emb_w, w1t);
    hipLaunchKernelGGL(w2bf_kernel, dim3(2304), dim3(256), 0, stream, unemb_w, w2_hi, w2_lo);
    hipLaunchKernelGGL(cbbf_kernel, dim3(2048), dim3(256), 0, stream, cb, cb_hi, cb_lo);
    hipLaunchKernelGGL(conv_emb_kernel, dim3(512, 2), dim3(256), 0, stream, z, w1t, emb_b, ze_t);
    hipLaunchKernelGGL(ln_kernel, dim3(NPIX), dim3(256), 0, stream, ze_t, ln_g, ln_b,
                       zf_bf, snorm, mu_a, r_a);
    hipMemsetAsync(gmax, 0, NPIX * sizeof(unsigned int), stream);
    hipMemsetAsync(ccnt, 0, NPIX * sizeof(int), stream);
    hipLaunchKernelGGL((screen_gemm_kernel<1>), dim3(256, 8), dim3(256), 0, stream,
                       zf_bf, cb_hi, gmax, ccnt, cand);
    hipLaunchKernelGGL((screen_gemm_kernel<2>), dim3(256, 8), dim3(256), 0, stream,
                       zf_bf, cb_hi, gmax, ccnt, cand);
    hipLaunchKernelGGL(rescore_kernel, dim3(NPIX / 4), dim3(256), 0, stream,
                       ze_t, mu_a, r_a, snorm, ln_g, ln_b, cb, ccnt, cand, idxi, idxf);
    hipLaunchKernelGGL(loss_partial_kernel, dim3(256), dim3(256), 0, stream, ze_t, cb, idxi, partials);
    hipLaunchKernelGGL(loss_final_kernel, dim3(1), dim3(256), 0, stream, partials, lossp);
    hipLaunchKernelGGL(conv_unemb_mfma, dim3(512, 2), dim3(256), 0, stream,
                       cb_hi, cb_lo, idxi, w2_hi, w2_lo, unemb_b, out);
}

// Round 5
// 766.409 us; speedup vs baseline: 4.6246x; 1.4959x over previous
//
#include <hip/hip_runtime.h>
#include <hip/hip_bf16.h>

#define B_SZ 16
#define CIN 256
#define EDIM 256
#define NE 8192
#define HW 32
#define NPIX (B_SZ*HW*HW)          // 16384
#define OUT_ELEMS (B_SZ*CIN*HW*HW) // 4194304
#define SCREEN_T 3.2e-4f
#define CAND_SLOTS 128

typedef __attribute__((ext_vector_type(8))) short short8;
typedef __attribute__((ext_vector_type(4))) short short4v;
typedef __attribute__((ext_vector_type(4))) float f32x4;

// ---------------- helpers ----------------
__device__ __forceinline__ float block_sum(float v, float* sbuf) {
    #pragma unroll
    for (int off = 32; off > 0; off >>= 1) v += __shfl_down(v, off, 64);
    int wid = threadIdx.x >> 6;
    int lane = threadIdx.x & 63;
    if (lane == 0) sbuf[wid] = v;
    __syncthreads();
    if (threadIdx.x == 0) sbuf[0] = sbuf[0] + sbuf[1] + sbuf[2] + sbuf[3];
    __syncthreads();
    float r = sbuf[0];
    __syncthreads();
    return r;
}

__device__ __forceinline__ double block_sum_d(double v, double* sbuf) {
    #pragma unroll
    for (int off = 32; off > 0; off >>= 1) v += __shfl_down(v, off, 64);
    int wid = threadIdx.x >> 6;
    int lane = threadIdx.x & 63;
    if (lane == 0) sbuf[wid] = v;
    __syncthreads();
    if (threadIdx.x == 0) sbuf[0] = (sbuf[0] + sbuf[1]) + (sbuf[2] + sbuf[3]);
    __syncthreads();
    double r = sbuf[0];
    __syncthreads();
    return r;
}

__device__ __forceinline__ unsigned short bf16rne(float f) {
    unsigned int u = __float_as_uint(f);
    unsigned int r = (u + 0x7FFFu + ((u >> 16) & 1u)) >> 16;
    return (unsigned short)r;
}
__device__ __forceinline__ float bf2f(unsigned short h) {
    return __uint_as_float((unsigned int)h << 16);
}

// monotone map float -> uint (order-preserving), and inverse
__device__ __forceinline__ unsigned int mapU(float f) {
    unsigned int u = __float_as_uint(f);
    return (u & 0x80000000u) ? ~u : (u | 0x80000000u);
}
__device__ __forceinline__ float unmapU(unsigned int m) {
    unsigned int u = (m & 0x80000000u) ? (m ^ 0x80000000u) : ~m;
    return __uint_as_float(u);
}

// ---------------- weight repack: dst[k*256 + o] = src[o*2304 + k] ----------------
__global__ void repack_w_kernel(const float* __restrict__ src, float* __restrict__ dst) {
    int k = blockIdx.x;      // 0..2303
    int o = threadIdx.x;     // 0..255
    dst[(size_t)k * 256 + o] = src[(size_t)o * 2304 + k];
}

// ---------------- unemb weights -> bf16 hi/lo, tap-major: d[cout][tap*256+e] ----------------
__global__ void w2bf_kernel(const float* __restrict__ src, unsigned short* __restrict__ dhi,
                            unsigned short* __restrict__ dlo) {
    int blk = blockIdx.x;        // cout*9 + tap
    int cout = blk / 9, tap = blk % 9;
    int e = threadIdx.x;
    float v = src[(size_t)cout * 2304 + e * 9 + tap];
    unsigned short h = bf16rne(v);
    unsigned short l = bf16rne(v - bf2f(h));
    size_t j = (size_t)cout * 2304 + tap * 256 + e;
    dhi[j] = h; dlo[j] = l;
}

// ---------------- codebook -> bf16 hi/lo ----------------
__global__ void cbbf_kernel(const float* __restrict__ cb, unsigned short* __restrict__ cb_hi,
                            unsigned short* __restrict__ cb_lo) {
    int i = blockIdx.x * 256 + threadIdx.x;   // 0..524287
    size_t base = (size_t)i * 4;
    float4 v = *(const float4*)(cb + base);
    short4v sh, sl;
    unsigned short h;
    h = bf16rne(v.x); sh[0] = (short)h; sl[0] = (short)bf16rne(v.x - bf2f(h));
    h = bf16rne(v.y); sh[1] = (short)h; sl[1] = (short)bf16rne(v.y - bf2f(h));
    h = bf16rne(v.z); sh[2] = (short)h; sl[2] = (short)bf16rne(v.z - bf2f(h));
    h = bf16rne(v.w); sh[3] = (short)h; sl[3] = (short)bf16rne(v.w - bf2f(h));
    *(short4v*)(cb_hi + base) = sh;
    *(short4v*)(cb_lo + base) = sl;
}

// ---------------- emb conv: z[B,C,H,W] -> ze[(b,h,w), e] (bit-exact arithmetic) ----------------
__global__ __launch_bounds__(256, 4) void conv_emb_kernel(const float* __restrict__ z,
                                                          const float* __restrict__ w1t,
                                                          const float* __restrict__ bias,
                                                          float* __restrict__ ze) {
    __shared__ float s[3 * 64 * 36];
    int bh = blockIdx.x;            // 0..511
    int b = bh >> 5, h = bh & 31;
    int e = (blockIdx.y << 7) + (threadIdx.x & 127);
    int wh = threadIdx.x >> 7;      // 0..1
    double accd[16];
    #pragma unroll
    for (int i = 0; i < 16; ++i) accd[i] = 0.0;
    for (int i = threadIdx.x; i < 3 * 64 * 36; i += 256) s[i] = 0.f;
    __syncthreads();

    for (int cc = 0; cc < 256; cc += 64) {
        for (int i = threadIdx.x; i < 3 * 64 * 32; i += 256) {
            int r = i >> 11;
            int c = (i >> 5) & 63;
            int w = i & 31;
            int hh = h + r - 1;
            float v = 0.f;
            if (hh >= 0 && hh < 32) v = z[(size_t)b * 262144 + (size_t)(cc + c) * 1024 + hh * 32 + w];
            s[(r * 64 + c) * 36 + (w + 1)] = v;
        }
        __syncthreads();
        for (int c = 0; c < 64; ++c) {
            const float* wrow = w1t + (size_t)(cc + c) * 9 * 256 + e;
            float tmp[16];
            #pragma unroll
            for (int i = 0; i < 16; ++i) tmp[i] = 0.f;
            #pragma unroll
            for (int r = 0; r < 3; ++r) {
                float v[20];
                const float* lrow = s + (r * 64 + c) * 36 + wh * 16;
                #pragma unroll
                for (int q = 0; q < 5; ++q) {
                    float4 t4 = *(const float4*)(lrow + q * 4);
                    v[q * 4 + 0] = t4.x; v[q * 4 + 1] = t4.y; v[q * 4 + 2] = t4.z; v[q * 4 + 3] = t4.w;
                }
                #pragma unroll
                for (int kw = 0; kw < 3; ++kw) {
                    float wv = wrow[(r * 3 + kw) * 256];
                    #pragma unroll
                    for (int i = 0; i < 16; ++i) tmp[i] = fmaf(v[i + kw], wv, tmp[i]);
                }
            }
            #pragma unroll
            for (int i = 0; i < 16; ++i) accd[i] += (double)tmp[i];
        }
        __syncthreads();
    }
    float bv = bias[e];
    int p0 = (b * 32 + h) * 32 + wh * 16;
    #pragma unroll
    for (int i = 0; i < 16; ++i) ze[(size_t)(p0 + i) * 256 + e] = (float)accd[i] + bv;
}

// ---------------- layernorm: emits zf_bf16, snorm, mu, rstd ----------------
__global__ void ln_kernel(const float* __restrict__ ze, const float* __restrict__ g,
                          const float* __restrict__ bta, unsigned short* __restrict__ zfb,
                          float* __restrict__ snorm, float* __restrict__ mu_a,
                          float* __restrict__ r_a) {
    __shared__ double sbuf[4];
    int p = blockIdx.x; int t = threadIdx.x;
    float x = ze[(size_t)p * 256 + t];
    double sum = block_sum_d((double)x, sbuf);
    float mu = ((float)sum) / 256.0f;
    float dev = x - mu;
    float sq = dev * dev;
    double vs = block_sum_d((double)sq, sbuf);
    float var = ((float)vs) / 256.0f;
    float r = 1.0f / sqrtf(var + 1e-5f);
    float y = ((dev * r) * g[t]) + bta[t];
    zfb[(size_t)p * 256 + t] = bf16rne(y);
    float ysq = y * y;
    double ss = block_sum_d((double)ysq, sbuf);
    if (t == 0) { snorm[p] = (float)ss; mu_a[p] = mu; r_a[p] = r; }
}

// ---------------- single-pass screening: B streamed from L2, no LDS tile, no main-loop barriers ----
// Block = 64-pixel tile (grid 256), 512 threads = 8 waves. Wave w owns n-rows c*128 + w*16 + l15.
// Per-pixel running max: per-lane regs, shfl-merged + LDS atomicMax every 8 steps (stale = safe).
// Candidates (dot >= runmax - T) collected into LDS; superset of true candidate set by monotonicity.
__global__ __launch_bounds__(512) void screen_kernel(const unsigned short* __restrict__ zf_bf,
                                                     const unsigned short* __restrict__ cb_bf,
                                                     int* __restrict__ ccnt,
                                                     int* __restrict__ cand) {
    __shared__ unsigned int smax[64];
    __shared__ int scnt[64];
    __shared__ int sbuf[64][CAND_SLOTS];   // 32 KB
    const int tid = threadIdx.x;
    const int w = tid >> 6;
    const int lane = tid & 63;
    const int l15 = lane & 15, lg = lane >> 4;
    const int p0 = blockIdx.x * 64;
    const int rowoff = w * 16 + l15;
    const int lg8 = lg * 8;

    if (tid < 64) { smax[tid] = 0u; scnt[tid] = 0; }
    __syncthreads();

    short8 aF[4][8];
    #pragma unroll
    for (int mf = 0; mf < 4; ++mf)
        #pragma unroll
        for (int ks = 0; ks < 8; ++ks)
            aF[mf][ks] = *reinterpret_cast<const short8*>(
                zf_bf + (size_t)(p0 + mf * 16 + l15) * 256 + ks * 32 + lg8);

    const f32x4 zero4 = {0.f, 0.f, 0.f, 0.f};
    float runL[4][4], runS[4][4];
    #pragma unroll
    for (int mf = 0; mf < 4; ++mf)
        #pragma unroll
        for (int r = 0; r < 4; ++r) { runL[mf][r] = -3.4e38f; runS[mf][r] = -3.4e38f; }

    // ---- seed pass: n = 0..1023, max only (bounds later insert counts) ----
    for (int c = 0; c < 8; ++c) {
        const int nrow = c * 128 + rowoff;
        const unsigned short* bp = cb_bf + (size_t)nrow * 256 + lg8;
        short8 bF[8];
        #pragma unroll
        for (int ks = 0; ks < 8; ++ks) bF[ks] = *reinterpret_cast<const short8*>(bp + ks * 32);
        f32x4 acc[4] = {zero4, zero4, zero4, zero4};
        #pragma unroll
        for (int ks = 0; ks < 8; ++ks)
            #pragma unroll
            for (int mf = 0; mf < 4; ++mf)
                acc[mf] = __builtin_amdgcn_mfma_f32_16x16x32_bf16(aF[mf][ks], bF[ks], acc[mf], 0, 0, 0);
        #pragma unroll
        for (int mf = 0; mf < 4; ++mf)
            #pragma unroll
            for (int r = 0; r < 4; ++r) runL[mf][r] = fmaxf(runL[mf][r], acc[mf][r]);
    }
    #pragma unroll
    for (int mf = 0; mf < 4; ++mf)
        #pragma unroll
        for (int r = 0; r < 4; ++r) {
            float v = runL[mf][r];
            v = fmaxf(v, __shfl_xor(v, 1, 64));
            v = fmaxf(v, __shfl_xor(v, 2, 64));
            v = fmaxf(v, __shfl_xor(v, 4, 64));
            v = fmaxf(v, __shfl_xor(v, 8, 64));
            runL[mf][r] = v;
            if (l15 == 0) atomicMax(&smax[mf * 16 + lg * 4 + r], mapU(v));
        }
    __syncthreads();
    #pragma unroll
    for (int mf = 0; mf < 4; ++mf)
        #pragma unroll
        for (int r = 0; r < 4; ++r) runS[mf][r] = unmapU(smax[mf * 16 + lg * 4 + r]);

    // ---- main pass: all n, with collection ----
    for (int c = 0; c < 64; ++c) {
        const int nrow = c * 128 + rowoff;
        const unsigned short* bp = cb_bf + (size_t)nrow * 256 + lg8;
        short8 bF[8];
        #pragma unroll
        for (int ks = 0; ks < 8; ++ks) bF[ks] = *reinterpret_cast<const short8*>(bp + ks * 32);
        f32x4 acc[4] = {zero4, zero4, zero4, zero4};
        #pragma unroll
        for (int ks = 0; ks < 8; ++ks)
            #pragma unroll
            for (int mf = 0; mf < 4; ++mf)
                acc[mf] = __builtin_amdgcn_mfma_f32_16x16x32_bf16(aF[mf][ks], bF[ks], acc[mf], 0, 0, 0);

        unsigned qual = 0u;
        #pragma unroll
        for (int mf = 0; mf < 4; ++mf)
            #pragma unroll
            for (int r = 0; r < 4; ++r) {
                float dd = acc[mf][r];
                if (dd >= fmaxf(runS[mf][r], runL[mf][r]) - SCREEN_T) qual |= (1u << (mf * 4 + r));
                runL[mf][r] = fmaxf(runL[mf][r], dd);
            }
        if (qual) {
            #pragma unroll
            for (int mf = 0; mf < 4; ++mf)
                #pragma unroll
                for (int r = 0; r < 4; ++r)
                    if (qual & (1u << (mf * 4 + r))) {
                        int pix = mf * 16 + lg * 4 + r;
                        int s = atomicAdd(&scnt[pix], 1);
                        if (s < CAND_SLOTS) sbuf[pix][s] = nrow;
                    }
        }
        if ((c & 7) == 7) {
            #pragma unroll
            for (int mf = 0; mf < 4; ++mf)
                #pragma unroll
                for (int r = 0; r < 4; ++r) {
                    float v = runL[mf][r];
                    v = fmaxf(v, __shfl_xor(v, 1, 64));
                    v = fmaxf(v, __shfl_xor(v, 2, 64));
                    v = fmaxf(v, __shfl_xor(v, 4, 64));
                    v = fmaxf(v, __shfl_xor(v, 8, 64));
                    runL[mf][r] = v;
                    if (l15 == 0) atomicMax(&smax[mf * 16 + lg * 4 + r], mapU(v));
                }
            #pragma unroll
            for (int mf = 0; mf < 4; ++mf)
                #pragma unroll
                for (int r = 0; r < 4; ++r) runS[mf][r] = unmapU(smax[mf * 16 + lg * 4 + r]);
        }
    }
    __syncthreads();
    if (tid < 64) ccnt[p0 + tid] = (scnt[tid] < CAND_SLOTS) ? scnt[tid] : CAND_SLOTS;
    for (int i = tid; i < 64 * CAND_SLOTS; i += 512) {
        int pix = i >> 7;                 // CAND_SLOTS == 128
        int s = i & (CAND_SLOTS - 1);
        if (s < scnt[pix] && s < CAND_SLOTS)
            cand[(size_t)(p0 + pix) * CAND_SLOTS + s] = sbuf[pix][s];
    }
}

// ---------------- exact rescore (bit-identical to round-2 dist arithmetic) ----------------
__global__ __launch_bounds__(256) void rescore_kernel(const float* __restrict__ ze,
                                                      const float* __restrict__ mu_a,
                                                      const float* __restrict__ r_a,
                                                      const float* __restrict__ snorm,
                                                      const float* __restrict__ g,
                                                      const float* __restrict__ bta,
                                                      const float* __restrict__ cb,
                                                      const int* __restrict__ ccnt,
                                                      const int* __restrict__ cand,
                                                      int* __restrict__ idx_i,
                                                      float* __restrict__ idx_f) {
    int p = blockIdx.x * 4 + (threadIdx.x >> 6);
    int lane = threadIdx.x & 63;
    int cnt = ccnt[p];
    if (cnt > CAND_SLOTS) cnt = CAND_SLOTS;
    float d = 3.4e38f;
    int ix = 0x7FFFFFFF;
    float mu = mu_a[p];
    float r = r_a[p];
    float sz = snorm[p];
    const float* zr = ze + (size_t)p * 256;
    for (int s = lane; s < cnt; s += 64) {
        int n = cand[(size_t)p * CAND_SLOTS + s];
        const float* cr = cb + (size_t)n * 256;
        float a0 = 0.f, a1 = 0.f, a2 = 0.f, a3 = 0.f;
        for (int k0 = 0; k0 < 256; k0 += 4) {
            float4 zq = *(const float4*)(zr + k0);
            float4 gq = *(const float4*)(g + k0);
            float4 bq = *(const float4*)(bta + k0);
            float4 cq = *(const float4*)(cr + k0);
            float d0 = zq.x - mu; float y0 = ((d0 * r) * gq.x) + bq.x;
            float d1 = zq.y - mu; float y1 = ((d1 * r) * gq.y) + bq.y;
            float d2 = zq.z - mu; float y2 = ((d2 * r) * gq.z) + bq.z;
            float d3 = zq.w - mu; float y3 = ((d3 * r) * gq.w) + bq.w;
            a0 = fmaf(y0, cq.x, a0);
            a1 = fmaf(y1, cq.y, a1);
            a2 = fmaf(y2, cq.z, a2);
            a3 = fmaf(y3, cq.w, a3);
        }
        float dot32 = (float)(((double)a0 + (double)a1) + ((double)a2 + (double)a3));
        float dd = fmaf(-2.0f, dot32, sz);
        if (dd < d || (dd == d && n < ix)) { d = dd; ix = n; }
    }
    #pragma unroll
    for (int off = 32; off > 0; off >>= 1) {
        float ov = __shfl_down(d, off, 64);
        int   oi = __shfl_down(ix, off, 64);
        if (ov < d || (ov == d && oi < ix)) { d = ov; ix = oi; }
    }
    if (lane == 0) {
        idx_i[p] = ix;
        idx_f[p] = (float)ix;
    }
}

// ---------------- loss ----------------
__global__ void loss_partial_kernel(const float* __restrict__ ze, const float* __restrict__ cb,
                                    const int* __restrict__ idx, float* __restrict__ partials) {
    __shared__ float sbuf[4];
    float sum = 0.f;
    const int total = NPIX * 256;
    for (int i = blockIdx.x * blockDim.x + threadIdx.x; i < total; i += gridDim.x * blockDim.x) {
        int p = i >> 8;
        int e = i & 255;
        float d = cb[(size_t)idx[p] * 256 + e] - ze[i];
        sum = fmaf(d, d, sum);
    }
    sum = block_sum(sum, sbuf);
    if (threadIdx.x == 0) partials[blockIdx.x] = sum;
}

__global__ void loss_final_kernel(const float* __restrict__ partials, float* __restrict__ loss_out) {
    __shared__ float sbuf[4];
    float v = partials[threadIdx.x];
    v = block_sum(v, sbuf);
    if (threadIdx.x == 0) *loss_out = v * (1.25f / (float)(NPIX * 256));
}

// ---------------- unemb conv as split-bf16 MFMA implicit GEMM ----------------
#define AROWB 128
#define ALO   13056
__global__ __launch_bounds__(256, 4) void conv_unemb_mfma(const unsigned short* __restrict__ cb_hi,
                                                          const unsigned short* __restrict__ cb_lo,
                                                          const int* __restrict__ idx,
                                                          const unsigned short* __restrict__ w2_hi,
                                                          const unsigned short* __restrict__ w2_lo,
                                                          const float* __restrict__ bias,
                                                          float* __restrict__ out) {
    __shared__ char smem[2 * ALO];
    float* ot = (float*)smem;
    const int tid = threadIdx.x;
    const int wid = tid >> 6, lane = tid & 63;
    const int l15 = lane & 15, lg = lane >> 4;
    const int bh = blockIdx.x;
    const int b = bh >> 5, h = bh & 31;
    const int ch = blockIdx.y;

    for (int i = tid; i < (2 * ALO) / 16; i += 256) ((int4*)smem)[i] = make_int4(0, 0, 0, 0);

    int nrow[3], rok[3], wpos[3], rr3[3];
    #pragma unroll
    for (int rd = 0; rd < 3; ++rd) {
        int t2 = rd * 256 + tid;
        int row = t2 >> 3;
        int r = row >> 5, w = row & 31;
        int hh = h + r - 1;
        rok[rd] = (hh >= 0 && hh < 32) ? 1 : 0;
        rr3[rd] = r; wpos[rd] = w;
        nrow[rd] = rok[rd] ? idx[(b * 32 + hh) * 32 + w] : 0;
    }
    __syncthreads();

    const f32x4 zero4 = {0.f, 0.f, 0.f, 0.f};
    f32x4 acc[2][2];
    acc[0][0] = zero4; acc[0][1] = zero4; acc[1][0] = zero4; acc[1][1] = zero4;

    for (int ec = 0; ec < 4; ++ec) {
        if (ec) __syncthreads();
        #pragma unroll
        for (int rd = 0; rd < 3; ++rd) {
            if (rok[rd]) {
                int t2 = rd * 256 + tid;
                int eo = (t2 & 7) * 8;
                size_t gsrc = (size_t)nrow[rd] * 256 + ec * 64 + eo;
                short8 vh = *(const short8*)(cb_hi + gsrc);
                short8 vl = *(const short8*)(cb_lo + gsrc);
                int wp = wpos[rd] + 1;
                int rowbase = (rr3[rd] * 34 + wp) * AROWB;
                int boff = (eo * 2) ^ ((wp & 7) << 4);
                *(short8*)(smem + rowbase + boff) = vh;
                *(short8*)(smem + ALO + rowbase + boff) = vl;
            }
        }
        __syncthreads();

        #pragma unroll
        for (int tap = 0; tap < 9; ++tap) {
            const int r = tap / 3, kw = tap % 3;
            #pragma unroll
            for (int ks = 0; ks < 2; ++ks) {
                int e2 = ks * 32 + lg * 8;
                short8 ah[2], al[2], bh2[2], bl2[2];
                #pragma unroll
                for (int mf = 0; mf < 2; ++mf) {
                    int wp = mf * 16 + l15 + kw;
                    int rowbase = (r * 34 + wp) * AROWB;
                    int boff = (e2 * 2) ^ ((wp & 7) << 4);
                    ah[mf] = *(const short8*)(smem + rowbase + boff);
                    al[mf] = *(const short8*)(smem + ALO + rowbase + boff);
                }
                #pragma unroll
                for (int nf = 0; nf < 2; ++nf) {
                    int cout = (ch << 7) + (wid << 5) + (nf << 4) + l15;
                    size_t goff = (size_t)cout * 2304 + tap * 256 + ec * 64 + e2;
                    bh2[nf] = *(const short8*)(w2_hi + goff);
                    bl2[nf] = *(const short8*)(w2_lo + goff);
                }
                #pragma unroll
                for (int mf = 0; mf < 2; ++mf)
                    #pragma unroll
                    for (int nf = 0; nf < 2; ++nf) {
                        acc[mf][nf] = __builtin_amdgcn_mfma_f32_16x16x32_bf16(ah[mf], bh2[nf], acc[mf][nf], 0, 0, 0);
                        acc[mf][nf] = __builtin_amdgcn_mfma_f32_16x16x32_bf16(ah[mf], bl2[nf], acc[mf][nf], 0, 0, 0);
                        acc[mf][nf] = __builtin_amdgcn_mfma_f32_16x16x32_bf16(al[mf], bh2[nf], acc[mf][nf], 0, 0, 0);
                    }
            }
        }
    }
    __syncthreads();
    #pragma unroll
    for (int mf = 0; mf < 2; ++mf)
        #pragma unroll
        for (int nf = 0; nf < 2; ++nf) {
            int cl = (wid << 5) + (nf << 4) + l15;
            #pragma unroll
            for (int rr = 0; rr < 4; ++rr) {
                int px = mf * 16 + lg * 4 + rr;
                ot[cl * 36 + px] = acc[mf][nf][rr];
            }
        }
    __syncthreads();
    int row = tid >> 1, half = tid & 1;
    int cout = (ch << 7) + row;
    float bv = bias[cout];
    float* dst = out + ((size_t)(b * 256 + cout) * 32 + h) * 32 + half * 16;
    const float* src = ot + row * 36 + half * 16;
    #pragma unroll
    for (int q = 0; q < 4; ++q) {
        float4 v = *(const float4*)(src + q * 4);
        v.x += bv; v.y += bv; v.z += bv; v.w += bv;
        *(float4*)(dst + q * 4) = v;
    }
}

extern "C" void kernel_launch(void* const* d_in, const int* in_sizes, int n_in,
                              void* d_out, int out_size, void* d_ws, size_t ws_size,
                              hipStream_t stream) {
    const float* z       = (const float*)d_in[0];
    const float* emb_w   = (const float*)d_in[1];
    const float* emb_b   = (const float*)d_in[2];
    const float* ln_g    = (const float*)d_in[3];
    const float* ln_b    = (const float*)d_in[4];
    const float* cb      = (const float*)d_in[5];
    const float* unemb_w = (const float*)d_in[6];
    const float* unemb_b = (const float*)d_in[7];

    float* out    = (float*)d_out;                    // [16,256,32,32]
    float* lossp  = out + OUT_ELEMS;                  // scalar
    float* idxf   = out + OUT_ELEMS + 1;              // [16384] as float

    // workspace layout (float slots), total ~47 MB
    float* ws = (float*)d_ws;
    float* ze_t = ws;                                               // 4,194,304
    unsigned short* zf_bf = (unsigned short*)(ze_t + (size_t)NPIX * 256);      // 2,097,152 fl
    unsigned short* cb_hi = (unsigned short*)((float*)zf_bf + 2097152);        // 1,048,576 fl
    unsigned short* cb_lo = (unsigned short*)((float*)cb_hi + 1048576);        // 1,048,576 fl
    float* snorm = (float*)cb_lo + 1048576;                         // 16,384
    float* mu_a  = snorm + NPIX;                                    // 16,384
    float* r_a   = mu_a + NPIX;                                     // 16,384
    float* w1t   = r_a + NPIX;                                      // 589,824
    unsigned short* w2_hi = (unsigned short*)(w1t + 2304 * 256);    // 294,912 fl
    unsigned short* w2_lo = (unsigned short*)((float*)w2_hi + 294912); // 294,912 fl
    int*   ccnt  = (int*)((float*)w2_lo + 294912);                  // 16,384
    int*   cand  = ccnt + NPIX;                                     // 2,097,152
    int*   idxi  = cand + (size_t)NPIX * CAND_SLOTS;                // 16,384
    float* partials = (float*)(idxi + NPIX);                        // 256

    hipLaunchKernelGGL(repack_w_kernel, dim3(2304), dim3(256), 0, stream, emb_w, w1t);
    hipLaunchKernelGGL(w2bf_kernel, dim3(2304), dim3(256), 0, stream, unemb_w, w2_hi, w2_lo);
    hipLaunchKernelGGL(cbbf_kernel, dim3(2048), dim3(256), 0, stream, cb, cb_hi, cb_lo);
    hipLaunchKernelGGL(conv_emb_kernel, dim3(512, 2), dim3(256), 0, stream, z, w1t, emb_b, ze_t);
    hipLaunchKernelGGL(ln_kernel, dim3(NPIX), dim3(256), 0, stream, ze_t, ln_g, ln_b,
                       zf_bf, snorm, mu_a, r_a);
    hipLaunchKernelGGL(screen_kernel, dim3(256), dim3(512), 0, stream, zf_bf, cb_hi, ccnt, cand);
    hipLaunchKernelGGL(rescore_kernel, dim3(NPIX / 4), dim3(256), 0, stream,
                       ze_t, mu_a, r_a, snorm, ln_g, ln_b, cb, ccnt, cand, idxi, idxf);
    hipLaunchKernelGGL(loss_partial_kernel, dim3(256), dim3(256), 0, stream, ze_t, cb, idxi, partials);
    hipLaunchKernelGGL(loss_final_kernel, dim3(1), dim3(256), 0, stream, partials, lossp);
    hipLaunchKernelGGL(conv_unemb_mfma, dim3(512, 2), dim3(256), 0, stream,
                       cb_hi, cb_lo, idxi, w2_hi, w2_lo, unemb_b, out);
}